// Round 4
// baseline (132.475 us; speedup 1.0000x reference)
//
#include <hip/hip_runtime.h>
#include <hip/hip_bf16.h>

typedef __bf16 bf16_t;
typedef bf16_t bf16x8 __attribute__((ext_vector_type(8)));
typedef float  f32x4  __attribute__((ext_vector_type(4)));
typedef float  f32x16 __attribute__((ext_vector_type(16)));
typedef int    i32x4  __attribute__((ext_vector_type(4)));

#define DH 64

// pack two floats into one u32 of 2 bf16 (RNE via cast)
__device__ __forceinline__ unsigned pkbf(float a, float b) {
    union { bf16_t h[2]; unsigned u; } z;
    z.h[0] = (bf16_t)a; z.h[1] = (bf16_t)b;
    return z.u;
}

// MFMA layout facts (HW-verified, guide m74/m101):
//   32x32 C/D: col = lane&31, row = (reg&3) + 8*(reg>>2) + 4*(lane>>5)
//   A: row = lane&31; B: col = lane&31; k-slot = (lane>>5)*8 + j.
//   (A/B k-maps only need mutual consistency -> bijection-safe.)

__global__ __launch_bounds__(512, 4)
void sdpa_fwd(const float* __restrict__ Qg, const float* __restrict__ Kg,
              const float* __restrict__ Vg, float* __restrict__ Og)
{
    __shared__ char lds[2 * 16384];   // per buf: K-img 8KB + V-img 8KB

    const int n   = blockIdx.x;
    const int qi  = 7 - (n >> 6);                       // heavy superstripe first
    const int bh  = ((n & 7) << 3) | ((n >> 3) & 7);    // bh clustered per XCD
    const int qS  = qi * 256;
    const int nkt = 4 * qi + 4;                         // tiles covering keys < qS+256

    const int t   = threadIdx.x;
    const int w   = t >> 6;
    const int l31 = t & 31;
    const int hi  = (t >> 5) & 1;
    const int swk = (l31 & 7) << 4;                     // kbuf read swizzle

    const size_t hoff = (size_t)bh * 2048 * DH;
    const float* Qh = Qg + hoff;
    const float* Kh = Kg + hoff;
    const float* Vh = Vg + hoff;
    float*       Oh = Og + hoff;

    const int qsb  = qS + w * 32;       // this wave's 32-row subtile
    const int qrow = qsb + l31;
    const int ktd  = qsb >> 6;          // the single diagonal (masked) tile

    // ---- Q fragments (B operand), pre-scaled by 1/8 (exact) ----
    bf16x8 qf[4];
#pragma unroll
    for (int sd = 0; sd < 4; ++sd) {
        const float* qp = Qh + (size_t)qrow * DH + sd * 16 + hi * 8;
        f32x4 a = *(const f32x4*)qp;
        f32x4 b = *(const f32x4*)(qp + 4);
        bf16x8 f;
        f[0] = (bf16_t)(a[0]*0.125f); f[1] = (bf16_t)(a[1]*0.125f);
        f[2] = (bf16_t)(a[2]*0.125f); f[3] = (bf16_t)(a[3]*0.125f);
        f[4] = (bf16_t)(b[0]*0.125f); f[5] = (bf16_t)(b[1]*0.125f);
        f[6] = (bf16_t)(b[2]*0.125f); f[7] = (bf16_t)(b[3]*0.125f);
        qf[sd] = f;
    }

    f32x16 acc0 = {}, acc1 = {};        // O^T fragments: d 0-31, 32-63
    float m_run = -1e30f, l_run = 0.0f;

    // staging map: thread -> (key row, 8-float d-chunk); fully coalesced
    const int skey = t >> 3;
    const int sdc  = t & 7;

    f32x4 rk0, rk1, rv0, rv1;           // T14 prefetch regs
    {
        const float* kp = Kh + (size_t)skey * DH + sdc * 8;
        rk0 = *(const f32x4*)kp;  rk1 = *(const f32x4*)(kp + 4);
        const float* vp = Vh + (size_t)skey * DH + sdc * 8;
        rv0 = *(const f32x4*)vp;  rv1 = *(const f32x4*)(vp + 4);
    }

    for (int kt = 0; kt < nkt; ++kt) {
        char* kb_ = lds + (kt & 1) * 16384;
        char* vb_ = kb_ + 8192;

        // ---- stage prefetched tile kt into buf[kt&1] ----
        {
            bf16x8 f;
            f[0] = (bf16_t)rk0[0]; f[1] = (bf16_t)rk0[1];
            f[2] = (bf16_t)rk0[2]; f[3] = (bf16_t)rk0[3];
            f[4] = (bf16_t)rk1[0]; f[5] = (bf16_t)rk1[1];
            f[6] = (bf16_t)rk1[2]; f[7] = (bf16_t)rk1[3];
            *(bf16x8*)(kb_ + ((skey * 128 + sdc * 16) ^ ((skey & 7) << 4))) = f;
            // V transpose scatter. SWZ(d) = (d&7)^(d>>3): write step jj has
            // d&7 = jj fixed but d>>3 = sdc varying -> ~2-way banks; read side
            // varies l31 -> also ~2-way. Static jj indexing (rule #20).
#pragma unroll
            for (int jj = 0; jj < 8; ++jj) {
                const float x = (jj < 4) ? rv0[jj & 3] : rv1[jj & 3];
                const int d = sdc * 8 + jj;
                *(bf16_t*)(vb_ + ((d * 128 + skey * 2) ^ ((jj ^ sdc) << 4))) = (bf16_t)x;
            }
        }
        // ---- issue next tile's global loads (in flight under compute) ----
        if (kt + 1 < nkt) {
            const float* kp = Kh + (size_t)((kt + 1) * 64 + skey) * DH + sdc * 8;
            rk0 = *(const f32x4*)kp;  rk1 = *(const f32x4*)(kp + 4);
            const float* vp = Vh + (size_t)((kt + 1) * 64 + skey) * DH + sdc * 8;
            rv0 = *(const f32x4*)vp;  rv1 = *(const f32x4*)(vp + 4);
        }
        __syncthreads();   // buf[kt&1] ready; also fences reuse 2 iters apart

        if (kt * 64 <= qsb + 31) {
            // ---- QK^T: tf[key_local][q], 2 key-blocks ----
            f32x16 tf0 = {}, tf1 = {};
#pragma unroll
            for (int sd = 0; sd < 4; ++sd) {
                const int inner = sd * 32 + hi * 16;
                const bf16x8 k0 = *(const bf16x8*)(kb_ + ((l31 * 128 + inner) ^ swk));
                const bf16x8 k1 = *(const bf16x8*)(kb_ + (((32 + l31) * 128 + inner) ^ swk));
                tf0 = __builtin_amdgcn_mfma_f32_32x32x16_bf16(k0, qf[sd], tf0, 0, 0, 0);
                tf1 = __builtin_amdgcn_mfma_f32_32x32x16_bf16(k1, qf[sd], tf1, 0, 0, 0);
            }

            if (kt == ktd) {   // only the diagonal tile needs element masking
#pragma unroll
                for (int r = 0; r < 16; ++r) {
                    const int krow = kt * 64 + (r & 3) + 8 * (r >> 2) + 4 * hi;
                    if (krow > qrow)      tf0[r] = -10000.0f;
                    if (krow + 32 > qrow) tf1[r] = -10000.0f;
                }
            }

            // ---- online softmax (row = q, spread over lane & lane^32) ----
            float mx = tf0[0];
#pragma unroll
            for (int r = 1; r < 16; ++r) mx = fmaxf(mx, tf0[r]);
#pragma unroll
            for (int r = 0; r < 16; ++r) mx = fmaxf(mx, tf1[r]);
            mx = fmaxf(mx, __shfl_xor(mx, 32));

            if (!__all(mx <= m_run + 8.0f)) {      // T13 defer-max
                const float mnew  = fmaxf(m_run, mx);
                const float alpha = __expf(m_run - mnew);
                m_run = mnew;
                l_run *= alpha;
                acc0 *= alpha;
                acc1 *= alpha;
            }

            float sum = 0.0f;
#pragma unroll
            for (int r = 0; r < 16; ++r) { tf0[r] = __expf(tf0[r] - m_run); sum += tf0[r]; }
#pragma unroll
            for (int r = 0; r < 16; ++r) { tf1[r] = __expf(tf1[r] - m_run); sum += tf1[r]; }
            sum += __shfl_xor(sum, 32);
            l_run += sum;

            // ---- pack P to bf16 pairs (per reg-group rg: regs rg*4..rg*4+3) ----
            unsigned P0[2][4], P1[2][4];
#pragma unroll
            for (int rg = 0; rg < 4; ++rg) {
                P0[0][rg] = pkbf(tf0[rg * 4 + 0], tf0[rg * 4 + 1]);
                P1[0][rg] = pkbf(tf0[rg * 4 + 2], tf0[rg * 4 + 3]);
                P0[1][rg] = pkbf(tf1[rg * 4 + 0], tf1[rg * 4 + 1]);
                P1[1][rg] = pkbf(tf1[rg * 4 + 2], tf1[rg * 4 + 3]);
            }

            // ---- PV: O^T += V^T · P^T, P redistributed in-register ----
#pragma unroll
            for (int s = 0; s < 4; ++s) {
                const int kb  = s >> 1;
                const int rgl = (s & 1) * 2, rgh = rgl + 1;
                int w0, w1, w2, w3;
#if defined(__has_builtin) && __has_builtin(__builtin_amdgcn_permlane32_swap)
                auto r0 = __builtin_amdgcn_permlane32_swap((int)P0[kb][rgl], (int)P0[kb][rgh], false, false);
                auto r1 = __builtin_amdgcn_permlane32_swap((int)P1[kb][rgl], (int)P1[kb][rgh], false, false);
                w0 = r0[0]; w2 = r0[1]; w1 = r1[0]; w3 = r1[1];
#else
                const int sa0 = __shfl_xor((int)P0[kb][rgl], 32);
                const int sb0 = __shfl_xor((int)P0[kb][rgh], 32);
                const int sa1 = __shfl_xor((int)P1[kb][rgl], 32);
                const int sb1 = __shfl_xor((int)P1[kb][rgh], 32);
                w0 = hi ? sb0 : (int)P0[kb][rgl];
                w2 = hi ? (int)P0[kb][rgh] : sa0;
                w1 = hi ? sb1 : (int)P1[kb][rgl];
                w3 = hi ? (int)P1[kb][rgh] : sa1;
#endif
                union { i32x4 i; bf16x8 v; } pz;
                pz.i = (i32x4){ w0, w1, w2, w3 };

                const int inner = s * 32 + hi * 16;
                const int d0 = l31;                  // acc0 rows: d 0..31
                const int d1 = 32 + l31;             // acc1 rows: d 32..63
                const int sz0 = ((d0 & 7) ^ (d0 >> 3)) << 4;
                const int sz1 = ((d1 & 7) ^ (d1 >> 3)) << 4;
                const bf16x8 v0 = *(const bf16x8*)(vb_ + ((d0 * 128 + inner) ^ sz0));
                const bf16x8 v1 = *(const bf16x8*)(vb_ + ((d1 * 128 + inner) ^ sz1));
                acc0 = __builtin_amdgcn_mfma_f32_32x32x16_bf16(v0, pz.v, acc0, 0, 0, 0);
                acc1 = __builtin_amdgcn_mfma_f32_32x32x16_bf16(v1, pz.v, acc1, 0, 0, 0);
            }
        }
    }

    // ---- epilogue: O[q][d] = acc^T / l ----
    const float inv = 1.0f / l_run;
    float* op = Oh + (size_t)qrow * DH;
#pragma unroll
    for (int rq = 0; rq < 4; ++rq) {
        f32x4 o0, o1;
#pragma unroll
        for (int j = 0; j < 4; ++j) { o0[j] = acc0[rq * 4 + j] * inv; o1[j] = acc1[rq * 4 + j] * inv; }
        *(f32x4*)(op + 8 * rq + 4 * hi)      = o0;
        *(f32x4*)(op + 32 + 8 * rq + 4 * hi) = o1;
    }
}

extern "C" void kernel_launch(void* const* d_in, const int* in_sizes, int n_in,
                              void* d_out, int out_size, void* d_ws, size_t ws_size,
                              hipStream_t stream) {
    (void)in_sizes; (void)n_in; (void)d_ws; (void)ws_size; (void)out_size;
    const float* q = (const float*)d_in[0];
    const float* k = (const float*)d_in[1];
    const float* v = (const float*)d_in[2];
    // d_in[3] (tril mask) applied analytically — identical semantics.
    float* out = (float*)d_out;
    hipLaunchKernelGGL(sdpa_fwd, dim3(512), dim3(512), 0, stream, q, k, v, out);
}

// Round 5
// 75.331 us; speedup vs baseline: 1.7586x; 1.7586x over previous
//
#include <hip/hip_runtime.h>
#include <hip/hip_bf16.h>

typedef __bf16 bf16_t;
typedef bf16_t bf16x8 __attribute__((ext_vector_type(8)));
typedef float  f32x4  __attribute__((ext_vector_type(4)));
typedef float  f32x16 __attribute__((ext_vector_type(16)));
typedef int    i32x4  __attribute__((ext_vector_type(4)));

#define DH 64

// pack two floats into one u32 of 2 bf16 (RNE via cast)
__device__ __forceinline__ unsigned pkbf(float a, float b) {
    union { bf16_t h[2]; unsigned u; } z;
    z.h[0] = (bf16_t)a; z.h[1] = (bf16_t)b;
    return z.u;
}

// MFMA layout facts (HW-verified, guide m74/m101; kernel-verified R4):
//   32x32 C/D: col = lane&31, row = (reg&3) + 8*(reg>>2) + 4*(lane>>5)
//   A: row = lane&31; B: col = lane&31; k-slot = (lane>>5)*8 + j.

__global__ __launch_bounds__(256, 2)
void sdpa_fwd(const float* __restrict__ Qg, const float* __restrict__ Kg,
              const float* __restrict__ Vg, float* __restrict__ Og)
{
    __shared__ char lds[2 * 16384];   // ring: per buf K-img 8KB + V-img 8KB

    const int n  = blockIdx.x;
    const int o  = ((n & 7) << 6) | (n >> 3);   // XCD-chunked swizzle (512%8==0)
    const int bh = o >> 3;                      // 0..63
    const int pr = o & 7;                       // stripe pair id

    const int t   = threadIdx.x;
    const int w   = t >> 6;                     // wave 0..3
    const int l31 = t & 31;
    const int hi  = (t >> 5) & 1;
    const int swk = (l31 & 7) << 4;             // kbuf read swizzle

    const size_t hoff = (size_t)bh * 2048 * DH;
    const float* Qh = Qg + hoff;
    const float* Kh = Kg + hoff;
    const float* Vh = Vg + hoff;
    float*       Oh = Og + hoff;

    // staging map: thread -> key rows {srow, srow+1}, d-chunk sdc*8..sdc*8+7
    const int srow = (t >> 3) * 2;
    const int sdc  = t & 7;

    // T14 prefetch regs: rk/rv [0..1]=row srow, [2..3]=row srow+1
    f32x4 rk[4], rv[4];
    {
        const float* kp = Kh + (size_t)srow * DH + sdc * 8;
        rk[0] = *(const f32x4*)kp;        rk[1] = *(const f32x4*)(kp + 4);
        rk[2] = *(const f32x4*)(kp + DH); rk[3] = *(const f32x4*)(kp + DH + 4);
        const float* vp = Vh + (size_t)srow * DH + sdc * 8;
        rv[0] = *(const f32x4*)vp;        rv[1] = *(const f32x4*)(vp + 4);
        rv[2] = *(const f32x4*)(vp + DH); rv[3] = *(const f32x4*)(vp + DH + 4);
    }

    const int stripes[2] = { 15 - pr, pr };   // heavy stripe first
    int gt = 0;                               // global staged-tile counter (buf parity)

    for (int s = 0; s < 2; ++s) {
        const int p    = stripes[s];
        const int qS   = p * 128;
        const int nkt  = 2 * p + 2;           // pair total = 34 (uniform)
        const int qsb  = qS + w * 32;         // this wave's 32-row subtile
        const int qrow = qsb + l31;
        const int ktd  = qsb >> 6;            // the single diagonal (masked) tile

        // ---- Q fragments (B operand), pre-scaled by 1/8 (exact) ----
        bf16x8 qf[4];
#pragma unroll
        for (int sd = 0; sd < 4; ++sd) {
            const float* qp = Qh + (size_t)qrow * DH + sd * 16 + hi * 8;
            f32x4 a = *(const f32x4*)qp;
            f32x4 b = *(const f32x4*)(qp + 4);
            bf16x8 f;
            f[0] = (bf16_t)(a[0]*0.125f); f[1] = (bf16_t)(a[1]*0.125f);
            f[2] = (bf16_t)(a[2]*0.125f); f[3] = (bf16_t)(a[3]*0.125f);
            f[4] = (bf16_t)(b[0]*0.125f); f[5] = (bf16_t)(b[1]*0.125f);
            f[6] = (bf16_t)(b[2]*0.125f); f[7] = (bf16_t)(b[3]*0.125f);
            qf[sd] = f;
        }

        f32x16 acc0 = {}, acc1 = {};          // O^T fragments: d 0-31, 32-63
        float m_run = -1e30f, l_run = 0.0f;

        for (int kt = 0; kt < nkt; ++kt, ++gt) {
            char* kb_ = lds + (gt & 1) * 16384;
            char* vb_ = kb_ + 8192;

            // ---- stage prefetched tile into buf[gt&1] ----
            {
#pragma unroll
                for (int r2 = 0; r2 < 2; ++r2) {     // two key rows
                    const int key = srow + r2;
                    bf16x8 f;
                    f[0] = (bf16_t)rk[r2*2][0]; f[1] = (bf16_t)rk[r2*2][1];
                    f[2] = (bf16_t)rk[r2*2][2]; f[3] = (bf16_t)rk[r2*2][3];
                    f[4] = (bf16_t)rk[r2*2+1][0]; f[5] = (bf16_t)rk[r2*2+1][1];
                    f[6] = (bf16_t)rk[r2*2+1][2]; f[7] = (bf16_t)rk[r2*2+1][3];
                    *(bf16x8*)(kb_ + ((key * 128 + sdc * 16) ^ ((key & 7) << 4))) = f;
                }
                // V transpose: pack key-pair per d -> b32 writes (2 lanes/bank)
#pragma unroll
                for (int jj = 0; jj < 8; ++jj) {
                    const int d  = sdc * 8 + jj;
                    const float x0 = (jj < 4) ? rv[0][jj & 3] : rv[1][jj & 3];
                    const float x1 = (jj < 4) ? rv[2][jj & 3] : rv[3][jj & 3];
                    *(unsigned*)(vb_ + ((d * 128 + srow * 2) ^ (((jj ^ sdc) & 7) << 4)))
                        = pkbf(x0, x1);
                }
            }
            // ---- issue next tile's global loads (in flight under compute) ----
            if (!(s == 1 && kt == nkt - 1)) {
                const int nk = (kt + 1 < nkt) ? kt + 1 : 0;  // next stripe restarts at 0
                const float* kp = Kh + (size_t)(nk * 64 + srow) * DH + sdc * 8;
                rk[0] = *(const f32x4*)kp;        rk[1] = *(const f32x4*)(kp + 4);
                rk[2] = *(const f32x4*)(kp + DH); rk[3] = *(const f32x4*)(kp + DH + 4);
                const float* vp = Vh + (size_t)(nk * 64 + srow) * DH + sdc * 8;
                rv[0] = *(const f32x4*)vp;        rv[1] = *(const f32x4*)(vp + 4);
                rv[2] = *(const f32x4*)(vp + DH); rv[3] = *(const f32x4*)(vp + DH + 4);
            }
            __syncthreads();   // buf[gt&1] ready

            if (kt * 64 <= qsb + 31) {
                // ---- QK^T: lane holds q = l31; 2 key blocks of 32 ----
                f32x16 tf0 = {}, tf1 = {};
#pragma unroll
                for (int sd = 0; sd < 4; ++sd) {
                    const int inner = sd * 32 + hi * 16;
                    const bf16x8 k0 = *(const bf16x8*)(kb_ + ((l31 * 128 + inner) ^ swk));
                    const bf16x8 k1 = *(const bf16x8*)(kb_ + (((32 + l31) * 128 + inner) ^ swk));
                    tf0 = __builtin_amdgcn_mfma_f32_32x32x16_bf16(k0, qf[sd], tf0, 0, 0, 0);
                    tf1 = __builtin_amdgcn_mfma_f32_32x32x16_bf16(k1, qf[sd], tf1, 0, 0, 0);
                }

                if (kt == ktd) {   // only the diagonal tile needs masking
#pragma unroll
                    for (int r = 0; r < 16; ++r) {
                        const int krow = kt * 64 + (r & 3) + 8 * (r >> 2) + 4 * hi;
                        if (krow > qrow)      tf0[r] = -10000.0f;
                        if (krow + 32 > qrow) tf1[r] = -10000.0f;
                    }
                }

                // ---- online softmax (row q spread over lane & lane^32) ----
                float mx = tf0[0];
#pragma unroll
                for (int r = 1; r < 16; ++r) mx = fmaxf(mx, tf0[r]);
#pragma unroll
                for (int r = 0; r < 16; ++r) mx = fmaxf(mx, tf1[r]);
                mx = fmaxf(mx, __shfl_xor(mx, 32));

                if (!__all(mx <= m_run + 8.0f)) {      // T13 defer-max
                    const float mnew  = fmaxf(m_run, mx);
                    const float alpha = __expf(m_run - mnew);
                    m_run = mnew;
                    l_run *= alpha;
                    acc0 *= alpha;
                    acc1 *= alpha;
                }

                float sum = 0.0f;
#pragma unroll
                for (int r = 0; r < 16; ++r) { tf0[r] = __expf(tf0[r] - m_run); sum += tf0[r]; }
#pragma unroll
                for (int r = 0; r < 16; ++r) { tf1[r] = __expf(tf1[r] - m_run); sum += tf1[r]; }
                sum += __shfl_xor(sum, 32);
                l_run += sum;

                // ---- pack P to bf16 pairs ----
                unsigned P0[2][4], P1[2][4];
#pragma unroll
                for (int rg = 0; rg < 4; ++rg) {
                    P0[0][rg] = pkbf(tf0[rg * 4 + 0], tf0[rg * 4 + 1]);
                    P1[0][rg] = pkbf(tf0[rg * 4 + 2], tf0[rg * 4 + 3]);
                    P0[1][rg] = pkbf(tf1[rg * 4 + 0], tf1[rg * 4 + 1]);
                    P1[1][rg] = pkbf(tf1[rg * 4 + 2], tf1[rg * 4 + 3]);
                }

                // ---- PV: O^T += V^T · P^T (P redistributed in-register) ----
#pragma unroll
                for (int sidx = 0; sidx < 4; ++sidx) {
                    const int kb  = sidx >> 1;
                    const int rgl = (sidx & 1) * 2, rgh = rgl + 1;
                    int w0, w1, w2, w3;
#if defined(__has_builtin) && __has_builtin(__builtin_amdgcn_permlane32_swap)
                    auto r0 = __builtin_amdgcn_permlane32_swap((int)P0[kb][rgl], (int)P0[kb][rgh], false, false);
                    auto r1 = __builtin_amdgcn_permlane32_swap((int)P1[kb][rgl], (int)P1[kb][rgh], false, false);
                    w0 = r0[0]; w2 = r0[1]; w1 = r1[0]; w3 = r1[1];
#else
                    const int sa0 = __shfl_xor((int)P0[kb][rgl], 32);
                    const int sb0 = __shfl_xor((int)P0[kb][rgh], 32);
                    const int sa1 = __shfl_xor((int)P1[kb][rgl], 32);
                    const int sb1 = __shfl_xor((int)P1[kb][rgh], 32);
                    w0 = hi ? sb0 : (int)P0[kb][rgl];
                    w2 = hi ? (int)P0[kb][rgh] : sa0;
                    w1 = hi ? sb1 : (int)P1[kb][rgl];
                    w3 = hi ? (int)P1[kb][rgh] : sa1;
#endif
                    union { i32x4 i; bf16x8 v; } pz;
                    pz.i = (i32x4){ w0, w1, w2, w3 };

                    const int inner = sidx * 32 + hi * 16;
                    const int d0 = l31;
                    const int d1 = 32 + l31;
                    const int sz0 = (((d0 & 7) ^ (d0 >> 3)) & 7) << 4;
                    const int sz1 = (((d1 & 7) ^ (d1 >> 3)) & 7) << 4;
                    const bf16x8 v0 = *(const bf16x8*)(vb_ + ((d0 * 128 + inner) ^ sz0));
                    const bf16x8 v1 = *(const bf16x8*)(vb_ + ((d1 * 128 + inner) ^ sz1));
                    acc0 = __builtin_amdgcn_mfma_f32_32x32x16_bf16(v0, pz.v, acc0, 0, 0, 0);
                    acc1 = __builtin_amdgcn_mfma_f32_32x32x16_bf16(v1, pz.v, acc1, 0, 0, 0);
                }
            }
        }

        // ---- stripe epilogue: O[q][d] = acc^T / l ----
        const float inv = 1.0f / l_run;
        float* op = Oh + (size_t)qrow * DH;
#pragma unroll
        for (int rq = 0; rq < 4; ++rq) {
            f32x4 o0, o1;
#pragma unroll
            for (int j = 0; j < 4; ++j) {
                o0[j] = acc0[rq * 4 + j] * inv;
                o1[j] = acc1[rq * 4 + j] * inv;
            }
            *(f32x4*)(op + 8 * rq + 4 * hi)      = o0;
            *(f32x4*)(op + 32 + 8 * rq + 4 * hi) = o1;
        }
    }
}

extern "C" void kernel_launch(void* const* d_in, const int* in_sizes, int n_in,
                              void* d_out, int out_size, void* d_ws, size_t ws_size,
                              hipStream_t stream) {
    (void)in_sizes; (void)n_in; (void)d_ws; (void)ws_size; (void)out_size;
    const float* q = (const float*)d_in[0];
    const float* k = (const float*)d_in[1];
    const float* v = (const float*)d_in[2];
    // d_in[3] (tril mask) applied analytically — identical semantics.
    float* out = (float*)d_out;
    hipLaunchKernelGGL(sdpa_fwd, dim3(512), dim3(256), 0, stream, q, k, v, out);
}